// Round 8
// baseline (62.248 us; speedup 1.0000x reference)
//
#include <hip/hip_runtime.h>
#include <math.h>

#define NN   65536
#define DEGC 16
#define DD   64
#define DD2  128
#define BB   1024
#define NEGC 10
#define NROWS (2 * BB + NEGC)      // 2058
#define NEDGE (NROWS * DEGC)       // 32928

__device__ __forceinline__ float tanh_fast(float x) {
    float t = __expf(2.0f * x);
    return 1.0f - 2.0f * __builtin_amdgcn_rcpf(t + 1.0f);
}

// ---------------------------------------------------------------------------
// K1: fused gather + GEMV1. Block b = graph row b (its 16 edges; 4 waves x 4).
//   buf[e] <- csum_e (gather);  buf[e] <- tanh([feat[n_e]|csum_e] @ W1^T + b1)
// Low-VGPR design: W1 in LDS (padded 65; per-lane b32 reads, 2-way free,
// shared across 4 edges); csum & self-row via uniform-address global float4
// loads (HW broadcast, VMEM pipe); in-place buf row (same-thread RAW order).
// ---------------------------------------------------------------------------
__global__ __launch_bounds__(256) void hop1_fused(
    const float* __restrict__ feat, const int* __restrict__ adj,
    const int* __restrict__ in1, const int* __restrict__ in2,
    const int* __restrict__ neg,
    const float* __restrict__ W1, const float* __restrict__ b1,
    float* __restrict__ buf) {

    __shared__ float wt[DD2 * 65];        // 33.3 KB, wt[i*65+j] = W1[j][i]

    int tid = threadIdx.x;
    #pragma unroll
    for (int t = 0; t < (DD * DD2) / 256; ++t) {
        int lin = t * 256 + tid;          // lin = j*128 + i
        int j = lin >> 7, i = lin & 127;
        wt[i * 65 + j] = W1[lin];         // write banks consecutive in i
    }

    int lane = tid & 63;
    int w = tid >> 6;
    int r = blockIdx.x;                   // one graph row per block
    int node = (r < BB) ? in1[r] : (r < 2 * BB ? in2[r - BB] : neg[r - 2 * BB]);
    node = __builtin_amdgcn_readfirstlane(node);

    // This wave's 4 edges: k = w*4 + m, e = r*16 + k.
    int n[4];
    #pragma unroll
    for (int m = 0; m < 4; ++m)
        n[m] = __builtin_amdgcn_readfirstlane(adj[node * DEGC + w * 4 + m]);

    int ebase = r * DEGC + w * 4;

    // Gather phase: per edge, 16 coalesced 256B rows -> tree sum -> buf row.
    #pragma unroll
    for (int m = 0; m < 4; ++m) {
        const int* arow = adj + n[m] * DEGC;      // uniform -> s_load
        float g[DEGC];
        #pragma unroll
        for (int k2 = 0; k2 < DEGC; ++k2)
            g[k2] = feat[arow[k2] * DD + lane];
        float p0 = (g[0] + g[1]) + (g[2] + g[3]);
        float p1 = (g[4] + g[5]) + (g[6] + g[7]);
        float p2 = (g[8] + g[9]) + (g[10] + g[11]);
        float p3 = (g[12] + g[13]) + (g[14] + g[15]);
        buf[(size_t)(ebase + m) * DD + lane] = (p0 + p1) + (p2 + p3);
    }

    __syncthreads();                      // wt staged (placed late: overlaps gather)

    float bias = b1[lane];
    float a0 = bias, a1 = bias, a2 = bias, a3 = bias;

    const float* f0 = feat + (size_t)n[0] * DD;
    const float* f1 = feat + (size_t)n[1] * DD;
    const float* f2 = feat + (size_t)n[2] * DD;
    const float* f3 = feat + (size_t)n[3] * DD;

    // Phase A: self features (cols 0..63), W from LDS, c uniform-broadcast.
    #pragma unroll
    for (int i4 = 0; i4 < 16; ++i4) {
        float w0 = wt[(i4 * 4 + 0) * 65 + lane];
        float w1v = wt[(i4 * 4 + 1) * 65 + lane];
        float w2v = wt[(i4 * 4 + 2) * 65 + lane];
        float w3v = wt[(i4 * 4 + 3) * 65 + lane];
        float4 c0 = *(const float4*)(f0 + i4 * 4);
        float4 c1 = *(const float4*)(f1 + i4 * 4);
        float4 c2 = *(const float4*)(f2 + i4 * 4);
        float4 c3 = *(const float4*)(f3 + i4 * 4);
        a0 += c0.x * w0 + c0.y * w1v + c0.z * w2v + c0.w * w3v;
        a1 += c1.x * w0 + c1.y * w1v + c1.z * w2v + c1.w * w3v;
        a2 += c2.x * w0 + c2.y * w1v + c2.z * w2v + c2.w * w3v;
        a3 += c3.x * w0 + c3.y * w1v + c3.z * w2v + c3.w * w3v;
    }
    // Phase B: neighbor sums (cols 64..127), c = own buf rows (uniform).
    const float* s0 = buf + (size_t)(ebase + 0) * DD;
    const float* s1 = buf + (size_t)(ebase + 1) * DD;
    const float* s2 = buf + (size_t)(ebase + 2) * DD;
    const float* s3 = buf + (size_t)(ebase + 3) * DD;
    #pragma unroll
    for (int i4 = 0; i4 < 16; ++i4) {
        float w0 = wt[(DD + i4 * 4 + 0) * 65 + lane];
        float w1v = wt[(DD + i4 * 4 + 1) * 65 + lane];
        float w2v = wt[(DD + i4 * 4 + 2) * 65 + lane];
        float w3v = wt[(DD + i4 * 4 + 3) * 65 + lane];
        float4 c0 = *(const float4*)(s0 + i4 * 4);
        float4 c1 = *(const float4*)(s1 + i4 * 4);
        float4 c2 = *(const float4*)(s2 + i4 * 4);
        float4 c3 = *(const float4*)(s3 + i4 * 4);
        a0 += c0.x * w0 + c0.y * w1v + c0.z * w2v + c0.w * w3v;
        a1 += c1.x * w0 + c1.y * w1v + c1.z * w2v + c1.w * w3v;
        a2 += c2.x * w0 + c2.y * w1v + c2.z * w2v + c2.w * w3v;
        a3 += c3.x * w0 + c3.y * w1v + c3.z * w2v + c3.w * w3v;
    }

    // In-place h1 write (per-thread program order vs the uniform reads above).
    buf[(size_t)(ebase + 0) * DD + lane] = tanh_fast(a0);
    buf[(size_t)(ebase + 1) * DD + lane] = tanh_fast(a1);
    buf[(size_t)(ebase + 2) * DD + lane] = tanh_fast(a2);
    buf[(size_t)(ebase + 3) * DD + lane] = tanh_fast(a3);
}

// ---------------------------------------------------------------------------
// K2: fused sum16 + GEMV2 + normalize (unchanged from R6).
// ---------------------------------------------------------------------------
__global__ __launch_bounds__(256) void hop2_fused(
    const float* __restrict__ feat, const float* __restrict__ h1,
    const int* __restrict__ in1, const int* __restrict__ in2,
    const int* __restrict__ neg,
    const float* __restrict__ W2, const float* __restrict__ b2,
    float* __restrict__ out) {

    __shared__ float4 q2[4096];           // 64 KB
    __shared__ float4 cs4[8][16];         // 2 KB

    int tid = threadIdx.x;
    {
        int j = tid & 127, g0 = tid >> 7;
        #pragma unroll
        for (int g = 0; g < 16; ++g) {
            int i4 = g0 * 16 + g;
            q2[(i4 << 7) | j] = *(const float4*)(W2 + j * DD2 + (i4 << 2));
        }
    }

    int lane = tid & 63;
    int w = tid >> 6;
    int r0 = blockIdx.x * 8 + w * 2;
    int r1 = r0 + 1;
    bool a0 = r0 < NROWS, a1 = r1 < NROWS;

    #pragma unroll
    for (int m = 0; m < 2; ++m) {
        int r = r0 + m;
        if (r < NROWS) {
            const float* base = h1 + (size_t)r * DEGC * DD;
            float s = 0.f;
            #pragma unroll
            for (int k = 0; k < DEGC; ++k)
                s += base[k * DD + lane];
            ((float*)&cs4[w * 2 + m][0])[lane] = s;
        }
    }
    __syncthreads();

    int node0 = a0 ? ((r0 < BB) ? in1[r0] : (r0 < 2 * BB ? in2[r0 - BB] : neg[r0 - 2 * BB])) : 0;
    int node1 = a1 ? ((r1 < BB) ? in1[r1] : (r1 < 2 * BB ? in2[r1 - BB] : neg[r1 - 2 * BB])) : node0;
    node0 = __builtin_amdgcn_readfirstlane(node0);
    node1 = __builtin_amdgcn_readfirstlane(node1);
    const float* cf0 = feat + node0 * DD;
    const float* cf1 = feat + node1 * DD;

    float A0 = b2[lane], B0 = b2[DD + lane];
    float A1 = A0, B1 = B0;

    #pragma unroll
    for (int i4 = 0; i4 < 16; ++i4) {
        float4 wA = q2[(i4 << 7) | lane];
        float4 wB = q2[(i4 << 7) | (64 + lane)];
        float4 c0 = *(const float4*)(cf0 + (i4 << 2));
        float4 c1 = *(const float4*)(cf1 + (i4 << 2));
        A0 += c0.x * wA.x + c0.y * wA.y + c0.z * wA.z + c0.w * wA.w;
        B0 += c0.x * wB.x + c0.y * wB.y + c0.z * wB.z + c0.w * wB.w;
        A1 += c1.x * wA.x + c1.y * wA.y + c1.z * wA.z + c1.w * wA.w;
        B1 += c1.x * wB.x + c1.y * wB.y + c1.z * wB.z + c1.w * wB.w;
    }
    #pragma unroll
    for (int i4 = 0; i4 < 16; ++i4) {
        float4 wA = q2[((16 + i4) << 7) | lane];
        float4 wB = q2[((16 + i4) << 7) | (64 + lane)];
        float4 c0 = cs4[w * 2 + 0][i4];
        float4 c1 = cs4[w * 2 + 1][i4];
        A0 += c0.x * wA.x + c0.y * wA.y + c0.z * wA.z + c0.w * wA.w;
        B0 += c0.x * wB.x + c0.y * wB.y + c0.z * wB.z + c0.w * wB.w;
        A1 += c1.x * wA.x + c1.y * wA.y + c1.z * wA.z + c1.w * wA.w;
        B1 += c1.x * wB.x + c1.y * wB.y + c1.z * wB.z + c1.w * wB.w;
    }

    if (a0) {
        float ss = A0 * A0 + B0 * B0;
        #pragma unroll
        for (int off = 32; off > 0; off >>= 1) ss += __shfl_xor(ss, off, 64);
        float inv = 1.0f / fmaxf(sqrtf(ss), 1e-12f);
        out[r0 * DD2 + lane]      = A0 * inv;
        out[r0 * DD2 + DD + lane] = B0 * inv;
    }
    if (a1) {
        float ss = A1 * A1 + B1 * B1;
        #pragma unroll
        for (int off = 32; off > 0; off >>= 1) ss += __shfl_xor(ss, off, 64);
        float inv = 1.0f / fmaxf(sqrtf(ss), 1e-12f);
        out[r1 * DD2 + lane]      = A1 * inv;
        out[r1 * DD2 + DD + lane] = B1 * inv;
    }
}

// ---------------------------------------------------------------------------
extern "C" void kernel_launch(void* const* d_in, const int* in_sizes, int n_in,
                              void* d_out, int out_size, void* d_ws, size_t ws_size,
                              hipStream_t stream) {
    const float* feat = (const float*)d_in[0];
    const int*   adj  = (const int*)d_in[1];
    const int*   in1  = (const int*)d_in[2];
    const int*   in2  = (const int*)d_in[3];
    const int*   neg  = (const int*)d_in[4];
    const float* W1   = (const float*)d_in[5];
    const float* b1   = (const float*)d_in[6];
    const float* W2   = (const float*)d_in[7];
    const float* b2   = (const float*)d_in[8];
    float* out = (float*)d_out;

    float* buf = (float*)d_ws;    // [NEDGE][64] f32 = 8.43 MB (csum -> h1 in place)

    hop1_fused<<<NROWS, 256, 0, stream>>>(feat, adj, in1, in2, neg, W1, b1, buf);
    hop2_fused<<<(NROWS + 7) / 8, 256, 0, stream>>>(
        feat, buf, in1, in2, neg, W2, b2, out);
}